// Round 2
// baseline (270.989 us; speedup 1.0000x reference)
//
#include <hip/hip_runtime.h>
#include <cstddef>

// StreamingISTFT fully fused: denorm+pack -> FFT32(k2) -> LDS -> FFT32(k1)
// -> window -> LDS frame tile -> overlap-add -> coalesced stores.
// B=8, F=1024(+Nyquist), T=2048, HOP=512, L=2048.
// irfft(2048) = complex IFFT(1024) (real-packing); IFFT(1024) = 32x32 four-step.
//
// R7: single-kernel fusion (OLA done in-block; boundary columns via atomicAdd).
// R8: XCD-aware remap (id%8=xcd, contiguous 32-tile runs per XCD) -- fixed the
//     3.2x input over-fetch; FETCH 446->67 MB, kernel 165->97 us.
// R9: occupancy restructure. rocprof: VALUBusy 40%, Occupancy 19.7%, memory
//     15% of peak -> latency-bound at 2 waves/SIMD (LDS 67.6 KB = 2 blocks/CU).
//     (a) r-split X: transpose tile holds only 16 of 32 r-slots; stage-2 waves
//         0-1 (q<16) read between the two half-writes, waves 2-3 after.
//     (b) F-half OLA: frame tile holds l<1024 then l>=1024; OLA partial sums
//         (c in {0,1}, then {2,3}) carried in 22 registers across the swap.
//     LDS 67584 -> 33792 B => 4 blocks/CU (16 waves/CU, 2x occupancy).
//     (c) Hermitian-pack twiddle hoisted: e^{i*pi*k/1024} = e^{i*pi*q/1024} *
//         C[k2] with exact 64th-root constant tables (replaces 64 sincos with
//         4 FMA each; accuracy equal or better -- no recurrence drift).
//     __launch_bounds__(256,4) caps VGPR at 128 to protect 4 waves/SIMD.

#define TDIM 2048
#define FDIM 1024
#define TT 8                    // t-columns per block
#define NTOT (512 * 2048)       // output samples per batch

static constexpr int kBREV[32] = {0,16,8,24,4,20,12,28,2,18,10,26,6,22,14,30,
                                  1,17,9,25,5,21,13,29,3,19,11,27,7,23,15,31};
// e^{+2*pi*i*r/32}, r=0..15 (inverse-transform sign)
static constexpr float kTR[16] = {
  1.0f, 0.98078528040323044f, 0.92387953251128674f, 0.83146961230254524f,
  0.70710678118654757f, 0.55557023301960218f, 0.38268343236508978f, 0.19509032201612825f,
  0.0f, -0.19509032201612825f, -0.38268343236508978f, -0.55557023301960218f,
  -0.70710678118654757f, -0.83146961230254524f, -0.92387953251128674f, -0.98078528040323044f};
static constexpr float kTI[16] = {
  0.0f, 0.19509032201612825f, 0.38268343236508978f, 0.55557023301960218f,
  0.70710678118654757f, 0.83146961230254524f, 0.92387953251128674f, 0.98078528040323044f,
  1.0f, 0.98078528040323044f, 0.92387953251128674f, 0.83146961230254524f,
  0.70710678118654757f, 0.55557023301960218f, 0.38268343236508978f, 0.19509032201612825f};
// 64th roots of unity: kCC[k2]=cos(2*pi*k2/64), kSS[k2]=sin(2*pi*k2/64)
static constexpr float kCC[32] = {
  1.0f, 0.99518472667219693f, 0.98078528040323044f, 0.95694033573220882f,
  0.92387953251128674f, 0.88192126434835505f, 0.83146961230254524f, 0.77301045336273699f,
  0.70710678118654757f, 0.63439328416364549f, 0.55557023301960218f, 0.47139673682599764f,
  0.38268343236508978f, 0.29028467725446233f, 0.19509032201612825f, 0.098017140329560604f,
  0.0f, -0.098017140329560604f, -0.19509032201612825f, -0.29028467725446233f,
  -0.38268343236508978f, -0.47139673682599764f, -0.55557023301960218f, -0.63439328416364549f,
  -0.70710678118654757f, -0.77301045336273699f, -0.83146961230254524f, -0.88192126434835505f,
  -0.92387953251128674f, -0.95694033573220882f, -0.98078528040323044f, -0.99518472667219693f};
static constexpr float kSS[32] = {
  0.0f, 0.098017140329560604f, 0.19509032201612825f, 0.29028467725446233f,
  0.38268343236508978f, 0.47139673682599764f, 0.55557023301960218f, 0.63439328416364549f,
  0.70710678118654757f, 0.77301045336273699f, 0.83146961230254524f, 0.88192126434835505f,
  0.92387953251128674f, 0.95694033573220882f, 0.98078528040323044f, 0.99518472667219693f,
  1.0f, 0.99518472667219693f, 0.98078528040323044f, 0.95694033573220882f,
  0.92387953251128674f, 0.88192126434835505f, 0.83146961230254524f, 0.77301045336273699f,
  0.70710678118654757f, 0.63439328416364549f, 0.55557023301960218f, 0.47139673682599764f,
  0.38268343236508978f, 0.29028467725446233f, 0.19509032201612825f, 0.098017140329560604f};

// One radix-2 stage, half-span H; literal indices after specialization -> SROA.
template <int H>
__device__ __forceinline__ void fft32_stage(float ar[32], float ai[32]) {
  constexpr int TSTEP = 16 / H;
  #pragma unroll
  for (int g = 0; g < 32; g += 2 * H) {
    #pragma unroll
    for (int j = 0; j < H; ++j) {
      const float twr = kTR[j * TSTEP];
      const float twi = kTI[j * TSTEP];
      const int i0 = g + j, i1 = i0 + H;
      const float tr = twr * ar[i1] - twi * ai[i1];
      const float ti = twr * ai[i1] + twi * ar[i1];
      ar[i1] = ar[i0] - tr; ai[i1] = ai[i0] - ti;
      ar[i0] += tr;         ai[i0] += ti;
    }
  }
}

// In-register radix-2 DIT FFT32 (inverse sign). Input bit-reversed; out natural.
__device__ __forceinline__ void ifft32_core(float ar[32], float ai[32]) {
  fft32_stage<1>(ar, ai);
  fft32_stage<2>(ar, ai);
  fft32_stage<4>(ar, ai);
  fft32_stage<8>(ar, ai);
  fft32_stage<16>(ar, ai);
}

// |v|^(2*PE) * KS via native v_log_f32 + v_exp_f32. v=0 -> 0: ok.
__device__ __forceinline__ float pow_gain(float v, float PE, float KS) {
  return KS * __builtin_amdgcn_exp2f(PE * __builtin_amdgcn_logf(v));
}

// Half-X layout: X(t, k1, rh) = k1*132 + rh*8 + t (rh in [0,16); 132 = 16*8+4).
// Stage-1 write lanes (t,k1): bank=(4*k1+t+8rh) -> uniform 2-way (free).
// Stage-2 read lanes (t,rh): bank=(8rh+t+4*k1) -> exactly 2-way (free).
// Max index 31*132+15*8+7 = 4219 < 4224 per component.
#define XH(t, k1, rh) ((k1) * 132 + (rh) * 8 + (t))
#define FST2 1029               // frame half-tile row stride (odd -> spread banks)

__global__ __launch_bounds__(256, 4) void istft_fused(const float* __restrict__ in,
                                                      const float* __restrict__ invw,
                                                      float* __restrict__ out) {
  __shared__ float buf[8448];           // 33.8 KB: Xh uses [0,8448), Fh reuses [0,8232)
  float* Xhr = buf;
  float* Xhi = buf + 4224;
  float* Fh  = buf;

  const int tid = threadIdx.x;
  const int tl  = tid & 7;              // t within tile
  const int q   = tid >> 3;             // k1 (stage 1) / r (stage 2)

  // XCD-aware remap (R8): each XCD owns 32 contiguous t-tiles of one batch.
  const int id   = blockIdx.x;          // 0..2047
  const int xcd  = id & 7;
  const int slot = id >> 3;             // 0..255
  const int b    = slot >> 5;           // 0..7
  const int tile = xcd * 32 + (slot & 31);  // 0..255
  const int t0   = tile * TT;
  const int t    = t0 + tl;

  const float* re_p = in + ((size_t)b * 2 + 0) * ((size_t)FDIM * TDIM);
  const float* im_p = in + ((size_t)b * 2 + 1) * ((size_t)FDIM * TDIM);

  const float KS = (float)(exp((-1.0 / 0.65) * log(0.06)) / 2048.0);
  const float PE = 7.0f / 26.0f;

  // ---- Stage 1: denorm + Hermitian pack + FFT32 over k2 ----
  float ar[32], ai[32];
  {
    // pack twiddle base: e^{i*pi*q/1024} (tiny angle -> high accuracy)
    const float aq = 3.0679615757712824e-3f * (float)q;
    const float wc = __cosf(aq), ws = __sinf(aq);
    #pragma unroll
    for (int k2 = 0; k2 < 32; ++k2) {
      const int k  = q + 32 * k2;
      const int km = (1024 - k) & 1023;
      const float x1 = re_p[(size_t)k  * TDIM + t];
      const float y1 = im_p[(size_t)k  * TDIM + t];
      const float x2 = re_p[(size_t)km * TDIM + t];
      const float y2 = im_p[(size_t)km * TDIM + t];
      const float g1 = pow_gain(x1 * x1 + y1 * y1, PE, KS);
      const float g2 = pow_gain(x2 * x2 + y2 * y2, PE, KS);
      const float s1r = x1 * g1, s1i = y1 * g1;
      const float s2r = x2 * g2, s2i = y2 * g2;
      // W[k] = (S1 + conj(S2)) + i*T*(S1 - conj(S2)),  T = e^{i pi k/1024}
      // T = e^{i pi q/1024} * e^{i pi k2/32}  (constant table, 4 FMA)
      const float cs = wc * kCC[k2] - ws * kSS[k2];
      const float sn = ws * kCC[k2] + wc * kSS[k2];
      const float Pre = s1r + s2r, Pim = s1i - s2i;
      const float Qre = s1r - s2r, Qim = s1i + s2i;
      const float u = cs * Qim + sn * Qre;
      const float v = cs * Qre - sn * Qim;
      float wr = Pre - u, wi = Pim + v;
      if (q == 0 && k2 == 0) { wr = s1r; wi = s1r; }  // DC: Im dropped, Nyquist=0
      ar[kBREV[k2]] = wr; ai[kBREV[k2]] = wi;
    }
    ifft32_core(ar, ai);
  }

  // ---- Transpose through half-size X (r-split) ----
  float zr[32], zi[32];
  // write half A: r in [0,16), with inter-stage twiddle e^{2 pi i q r/1024}
  #pragma unroll
  for (int r = 0; r < 16; ++r) {
    const float ang = 6.1359231515425649e-3f * (float)(q * r);
    const float sn = __sinf(ang), cs = __cosf(ang);
    Xhr[XH(tl, q, r)] = cs * ar[r] - sn * ai[r];
    Xhi[XH(tl, q, r)] = cs * ai[r] + sn * ar[r];
  }
  __syncthreads();
  if (q < 16) {                         // waves 0-1 read their stage-2 input
    #pragma unroll
    for (int i = 0; i < 32; ++i) {      // bit-reversed k1 load order
      zr[i] = Xhr[XH(tl, kBREV[i], q)];
      zi[i] = Xhi[XH(tl, kBREV[i], q)];
    }
  }
  __syncthreads();
  // write half B: r in [16,32) into the same slots
  #pragma unroll
  for (int r = 16; r < 32; ++r) {
    const float ang = 6.1359231515425649e-3f * (float)(q * r);
    const float sn = __sinf(ang), cs = __cosf(ang);
    Xhr[XH(tl, q, r - 16)] = cs * ar[r] - sn * ai[r];
    Xhi[XH(tl, q, r - 16)] = cs * ai[r] + sn * ar[r];
  }
  __syncthreads();
  if (q >= 16) {                        // waves 2-3 read their stage-2 input
    #pragma unroll
    for (int i = 0; i < 32; ++i) {
      zr[i] = Xhr[XH(tl, kBREV[i], q - 16)];
      zi[i] = Xhi[XH(tl, kBREV[i], q - 16)];
    }
  }
  __syncthreads();                      // X dead; Fh may overwrite buf

  // ---- Stage 2: FFT32 over k1 ----
  ifft32_core(zr, zi);

  // ---- Windowed frame halves + OLA with register-carried partials ----
  // frames[tl][l], l = 2*(q+32s)+{0,1}; s<16 <=> l<1024.
  float* ob = out + (size_t)b * NTOT;
  float acc[11][2] = {};

  // F half A (l < 1024)
  #pragma unroll
  for (int s = 0; s < 16; ++s) {
    const int l0 = 2 * q + 64 * s;
    Fh[tl * FST2 + l0]     = zr[s] * invw[l0];
    Fh[tl * FST2 + l0 + 1] = zi[s] * invw[l0 + 1];
  }
  __syncthreads();
  // OLA contributions c in {0,1}: sample l = j + 512c < 1024
  #pragma unroll
  for (int rel = 0; rel < 11; ++rel) {
    if (t0 + rel > 2047) continue;
    #pragma unroll
    for (int half = 0; half < 2; ++half) {
      const int j = tid + 256 * half;
      float v = 0.0f;
      #pragma unroll
      for (int c = 0; c < 2; ++c) {
        const int tt = rel - c;
        if (tt >= 0 && tt < TT) v += Fh[tt * FST2 + j + 512 * c];
      }
      acc[rel][half] = v;
    }
  }
  __syncthreads();
  // F half B (l >= 1024), stored at l-1024
  #pragma unroll
  for (int s = 16; s < 32; ++s) {
    const int l0 = 2 * q + 64 * s;
    const int lp = l0 - 1024;
    Fh[tl * FST2 + lp]     = zr[s] * invw[l0];
    Fh[tl * FST2 + lp + 1] = zi[s] * invw[l0 + 1];
  }
  __syncthreads();
  // OLA contributions c in {2,3} (sample l-1024 = j + 512(c-2)) + store
  #pragma unroll
  for (int rel = 0; rel < 11; ++rel) {
    const int tp = t0 + rel;
    if (tp > 2047) continue;
    #pragma unroll
    for (int half = 0; half < 2; ++half) {
      const int j = tid + 256 * half;
      float v = acc[rel][half];
      #pragma unroll
      for (int c = 2; c < 4; ++c) {
        const int tt = rel - c;
        if (tt >= 0 && tt < TT) v += Fh[tt * FST2 + j + 512 * (c - 2)];
      }
      const int n = tp * 512 + j;
      if (rel >= 3 && rel <= 7) ob[n] = v;          // all 4 contributors in-block
      else atomicAdd(&ob[n], v);                     // tile boundary: 2 writers
    }
  }
}

extern "C" void kernel_launch(void* const* d_in, const int* in_sizes, int n_in,
                              void* d_out, int out_size, void* d_ws, size_t ws_size,
                              hipStream_t stream) {
  (void)in_sizes; (void)n_in; (void)d_ws; (void)ws_size;
  const float* in   = (const float*)d_in[0];
  const float* invw = (const float*)d_in[1];
  float* out = (float*)d_out;
  hipMemsetAsync(out, 0, (size_t)out_size * sizeof(float), stream);
  istft_fused<<<dim3(TDIM / TT * 8), 256, 0, stream>>>(in, invw, out);
}

// Round 3
// 246.202 us; speedup vs baseline: 1.1007x; 1.1007x over previous
//
#include <hip/hip_runtime.h>
#include <cstddef>

// StreamingISTFT fully fused: denorm+pack -> FFT32(k2) -> LDS -> FFT32(k1)
// -> window -> LDS frame tile -> overlap-add -> coalesced stores.
// B=8, F=1024(+Nyquist), T=2048, HOP=512, L=2048.
// irfft(2048) = complex IFFT(1024) (real-packing); IFFT(1024) = 32x32 four-step.
//
// R7: single-kernel fusion (OLA in-block; boundary columns via atomicAdd).
// R8: XCD-aware remap (id%8=xcd, contiguous 32-tile runs per XCD): FETCH
//     446->67 MB, kernel 165->97 us.
// R9: LDS 67.6->33.8 KB (r-split X + l-split F). Occupancy 19.7->37% BUT the
//     22-reg OLA carry spilled (launch_bounds(256,4) let the allocator target
//     the 64-VGPR bin): FETCH/WRITE +48/+71 MB of scratch, kernel 97->125 us.
// R10: same LDS plan, spill-proof OLA carry. F split by FRAME (tt 0..3 then
//     4..7) instead of sample-half: rel 0..3 complete in phase A, rel 7..10 in
//     phase B, only rel 4..6 carried -> acc[3][2] = 6 regs (was 22). Plain
//     __launch_bounds__(256) (no min-waves hint -> no 64-VGPR spill target).
//     Expect VGPR ~110 -> 4 blocks/CU (LDS-limited), no scratch.

#define TDIM 2048
#define FDIM 1024
#define TT 8                    // t-columns per block
#define NTOT (512 * 2048)       // output samples per batch

static constexpr int kBREV[32] = {0,16,8,24,4,20,12,28,2,18,10,26,6,22,14,30,
                                  1,17,9,25,5,21,13,29,3,19,11,27,7,23,15,31};
// e^{+2*pi*i*r/32}, r=0..15 (inverse-transform sign)
static constexpr float kTR[16] = {
  1.0f, 0.98078528040323044f, 0.92387953251128674f, 0.83146961230254524f,
  0.70710678118654757f, 0.55557023301960218f, 0.38268343236508978f, 0.19509032201612825f,
  0.0f, -0.19509032201612825f, -0.38268343236508978f, -0.55557023301960218f,
  -0.70710678118654757f, -0.83146961230254524f, -0.92387953251128674f, -0.98078528040323044f};
static constexpr float kTI[16] = {
  0.0f, 0.19509032201612825f, 0.38268343236508978f, 0.55557023301960218f,
  0.70710678118654757f, 0.83146961230254524f, 0.92387953251128674f, 0.98078528040323044f,
  1.0f, 0.98078528040323044f, 0.92387953251128674f, 0.83146961230254524f,
  0.70710678118654757f, 0.55557023301960218f, 0.38268343236508978f, 0.19509032201612825f};
// 64th roots of unity: kCC[k2]=cos(2*pi*k2/64), kSS[k2]=sin(2*pi*k2/64)
static constexpr float kCC[32] = {
  1.0f, 0.99518472667219693f, 0.98078528040323044f, 0.95694033573220882f,
  0.92387953251128674f, 0.88192126434835505f, 0.83146961230254524f, 0.77301045336273699f,
  0.70710678118654757f, 0.63439328416364549f, 0.55557023301960218f, 0.47139673682599764f,
  0.38268343236508978f, 0.29028467725446233f, 0.19509032201612825f, 0.098017140329560604f,
  0.0f, -0.098017140329560604f, -0.19509032201612825f, -0.29028467725446233f,
  -0.38268343236508978f, -0.47139673682599764f, -0.55557023301960218f, -0.63439328416364549f,
  -0.70710678118654757f, -0.77301045336273699f, -0.83146961230254524f, -0.88192126434835505f,
  -0.92387953251128674f, -0.95694033573220882f, -0.98078528040323044f, -0.99518472667219693f};
static constexpr float kSS[32] = {
  0.0f, 0.098017140329560604f, 0.19509032201612825f, 0.29028467725446233f,
  0.38268343236508978f, 0.47139673682599764f, 0.55557023301960218f, 0.63439328416364549f,
  0.70710678118654757f, 0.77301045336273699f, 0.83146961230254524f, 0.88192126434835505f,
  0.92387953251128674f, 0.95694033573220882f, 0.98078528040323044f, 0.99518472667219693f,
  1.0f, 0.99518472667219693f, 0.98078528040323044f, 0.95694033573220882f,
  0.92387953251128674f, 0.88192126434835505f, 0.83146961230254524f, 0.77301045336273699f,
  0.70710678118654757f, 0.63439328416364549f, 0.55557023301960218f, 0.47139673682599764f,
  0.38268343236508978f, 0.29028467725446233f, 0.19509032201612825f, 0.098017140329560604f};

// One radix-2 stage, half-span H; literal indices after specialization -> SROA.
template <int H>
__device__ __forceinline__ void fft32_stage(float ar[32], float ai[32]) {
  constexpr int TSTEP = 16 / H;
  #pragma unroll
  for (int g = 0; g < 32; g += 2 * H) {
    #pragma unroll
    for (int j = 0; j < H; ++j) {
      const float twr = kTR[j * TSTEP];
      const float twi = kTI[j * TSTEP];
      const int i0 = g + j, i1 = i0 + H;
      const float tr = twr * ar[i1] - twi * ai[i1];
      const float ti = twr * ai[i1] + twi * ar[i1];
      ar[i1] = ar[i0] - tr; ai[i1] = ai[i0] - ti;
      ar[i0] += tr;         ai[i0] += ti;
    }
  }
}

// In-register radix-2 DIT FFT32 (inverse sign). Input bit-reversed; out natural.
__device__ __forceinline__ void ifft32_core(float ar[32], float ai[32]) {
  fft32_stage<1>(ar, ai);
  fft32_stage<2>(ar, ai);
  fft32_stage<4>(ar, ai);
  fft32_stage<8>(ar, ai);
  fft32_stage<16>(ar, ai);
}

// |v|^(2*PE) * KS via native v_log_f32 + v_exp_f32. v=0 -> 0: ok.
__device__ __forceinline__ float pow_gain(float v, float PE, float KS) {
  return KS * __builtin_amdgcn_exp2f(PE * __builtin_amdgcn_logf(v));
}

// Half-X layout: X(t, k1, rh) = k1*132 + rh*8 + t (rh in [0,16); 132 = 16*8+4).
// Stage-1 write lanes (t,k1): bank=(4k1+t+8rh) -> near-uniform (free). Stage-2
// read lanes (t,rh): bank=(8rh+t+4k1) -> exactly 2-way (free). Max 4219 < 4224.
#define XH(t, k1, rh) ((k1) * 132 + (rh) * 8 + (t))
#define FSTR 2053               // frame tile row stride (odd -> spread banks)

__global__ __launch_bounds__(256) void istft_fused(const float* __restrict__ in,
                                                   const float* __restrict__ invw,
                                                   float* __restrict__ out) {
  __shared__ float buf[8448];           // 33.8 KB: Xh [0,8448); F-4frames [0,8207)
  float* Xhr = buf;
  float* Xhi = buf + 4224;
  float* Fh  = buf;

  const int tid = threadIdx.x;
  const int tl  = tid & 7;              // t within tile
  const int q   = tid >> 3;             // k1 (stage 1) / r (stage 2)

  // XCD-aware remap (R8): each XCD owns 32 contiguous t-tiles of one batch.
  const int id   = blockIdx.x;          // 0..2047
  const int xcd  = id & 7;
  const int slot = id >> 3;             // 0..255
  const int b    = slot >> 5;           // 0..7
  const int tile = xcd * 32 + (slot & 31);  // 0..255
  const int t0   = tile * TT;
  const int t    = t0 + tl;

  const float* re_p = in + ((size_t)b * 2 + 0) * ((size_t)FDIM * TDIM);
  const float* im_p = in + ((size_t)b * 2 + 1) * ((size_t)FDIM * TDIM);

  const float KS = (float)(exp((-1.0 / 0.65) * log(0.06)) / 2048.0);
  const float PE = 7.0f / 26.0f;

  // ---- Stage 1: denorm + Hermitian pack + FFT32 over k2 ----
  float ar[32], ai[32];
  {
    // pack twiddle base: e^{i*pi*q/1024}; T = base * e^{i*pi*k2/32} (tables)
    const float aq = 3.0679615757712824e-3f * (float)q;
    const float wc = __cosf(aq), ws = __sinf(aq);
    #pragma unroll
    for (int k2 = 0; k2 < 32; ++k2) {
      const int k  = q + 32 * k2;
      const int km = (1024 - k) & 1023;
      const float x1 = re_p[(size_t)k  * TDIM + t];
      const float y1 = im_p[(size_t)k  * TDIM + t];
      const float x2 = re_p[(size_t)km * TDIM + t];
      const float y2 = im_p[(size_t)km * TDIM + t];
      const float g1 = pow_gain(x1 * x1 + y1 * y1, PE, KS);
      const float g2 = pow_gain(x2 * x2 + y2 * y2, PE, KS);
      const float s1r = x1 * g1, s1i = y1 * g1;
      const float s2r = x2 * g2, s2i = y2 * g2;
      // W[k] = (S1 + conj(S2)) + i*T*(S1 - conj(S2)),  T = e^{i pi k/1024}
      const float cs = wc * kCC[k2] - ws * kSS[k2];
      const float sn = ws * kCC[k2] + wc * kSS[k2];
      const float Pre = s1r + s2r, Pim = s1i - s2i;
      const float Qre = s1r - s2r, Qim = s1i + s2i;
      const float u = cs * Qim + sn * Qre;
      const float v = cs * Qre - sn * Qim;
      float wr = Pre - u, wi = Pim + v;
      if (q == 0 && k2 == 0) { wr = s1r; wi = s1r; }  // DC: Im dropped, Nyquist=0
      ar[kBREV[k2]] = wr; ai[kBREV[k2]] = wi;
    }
    ifft32_core(ar, ai);
  }

  // ---- Transpose through half-size X (r-split) ----
  float zr[32], zi[32];
  // write half A: r in [0,16), with inter-stage twiddle e^{2 pi i q r/1024}
  #pragma unroll
  for (int r = 0; r < 16; ++r) {
    const float ang = 6.1359231515425649e-3f * (float)(q * r);
    const float sn = __sinf(ang), cs = __cosf(ang);
    Xhr[XH(tl, q, r)] = cs * ar[r] - sn * ai[r];
    Xhi[XH(tl, q, r)] = cs * ai[r] + sn * ar[r];
  }
  __syncthreads();
  if (q < 16) {                         // waves 0-1 read their stage-2 input
    #pragma unroll
    for (int i = 0; i < 32; ++i) {      // bit-reversed k1 load order
      zr[i] = Xhr[XH(tl, kBREV[i], q)];
      zi[i] = Xhi[XH(tl, kBREV[i], q)];
    }
  }
  __syncthreads();
  // write half B: r in [16,32) into the same slots
  #pragma unroll
  for (int r = 16; r < 32; ++r) {
    const float ang = 6.1359231515425649e-3f * (float)(q * r);
    const float sn = __sinf(ang), cs = __cosf(ang);
    Xhr[XH(tl, q, r - 16)] = cs * ar[r] - sn * ai[r];
    Xhi[XH(tl, q, r - 16)] = cs * ai[r] + sn * ar[r];
  }
  __syncthreads();
  if (q >= 16) {                        // waves 2-3 read their stage-2 input
    #pragma unroll
    for (int i = 0; i < 32; ++i) {
      zr[i] = Xhr[XH(tl, kBREV[i], q - 16)];
      zi[i] = Xhi[XH(tl, kBREV[i], q - 16)];
    }
  }
  __syncthreads();                      // X dead; F tile may overwrite buf

  // ---- Stage 2: FFT32 over k1 ----
  ifft32_core(zr, zi);

  // ---- Frame-split OLA: frames tt in [0,4) then [4,8) ----
  // frames[tl][l], l = 2*(q+32s)+{0,1}. Contributor of out col rel: tt=rel-c.
  // Phase A completes rel 0..3; phase B completes rel 4..10; only rel 4..6
  // carry partials across the swap (6 registers).
  float* ob = out + (size_t)b * NTOT;
  float acc[3][2];

  // F phase A: frames tl in [0,4)
  if (tl < 4) {
    #pragma unroll
    for (int s = 0; s < 32; ++s) {
      const int l0 = 2 * q + 64 * s;
      Fh[tl * FSTR + l0]     = zr[s] * invw[l0];
      Fh[tl * FSTR + l0 + 1] = zi[s] * invw[l0 + 1];
    }
  }
  __syncthreads();
  // OLA phase A: contributors with tt = rel-c in [0,4)
  #pragma unroll
  for (int rel = 0; rel < 7; ++rel) {
    #pragma unroll
    for (int half = 0; half < 2; ++half) {
      const int j = tid + 256 * half;
      float v = 0.0f;
      #pragma unroll
      for (int c = 0; c < 4; ++c) {
        const int tt = rel - c;
        if (tt >= 0 && tt < 4) v += Fh[tt * FSTR + j + 512 * c];
      }
      if (rel < 3)       atomicAdd(&ob[(t0 + rel) * 512 + j], v);  // boundary
      else if (rel == 3) ob[(t0 + rel) * 512 + j] = v;             // complete
      else               acc[rel - 4][half] = v;                   // carry 4..6
    }
  }
  __syncthreads();
  // F phase B: frames tl in [4,8), stored at row tl-4
  if (tl >= 4) {
    #pragma unroll
    for (int s = 0; s < 32; ++s) {
      const int l0 = 2 * q + 64 * s;
      Fh[(tl - 4) * FSTR + l0]     = zr[s] * invw[l0];
      Fh[(tl - 4) * FSTR + l0 + 1] = zi[s] * invw[l0 + 1];
    }
  }
  __syncthreads();
  // OLA phase B: contributors with tt = rel-c in [4,8) (row tt-4)
  #pragma unroll
  for (int rel = 4; rel < 11; ++rel) {
    const int tp = t0 + rel;
    if (tp > 2047) continue;
    #pragma unroll
    for (int half = 0; half < 2; ++half) {
      const int j = tid + 256 * half;
      float v = (rel < 7) ? acc[rel - 4][half] : 0.0f;
      #pragma unroll
      for (int c = 0; c < 4; ++c) {
        const int tt = rel - c;
        if (tt >= 4 && tt < 8) v += Fh[(tt - 4) * FSTR + j + 512 * c];
      }
      const int n = tp * 512 + j;
      if (rel <= 7) ob[n] = v;          // all 4 contributors seen in-block
      else atomicAdd(&ob[n], v);        // tile boundary: 2 writers
    }
  }
}

extern "C" void kernel_launch(void* const* d_in, const int* in_sizes, int n_in,
                              void* d_out, int out_size, void* d_ws, size_t ws_size,
                              hipStream_t stream) {
  (void)in_sizes; (void)n_in; (void)d_ws; (void)ws_size;
  const float* in   = (const float*)d_in[0];
  const float* invw = (const float*)d_in[1];
  float* out = (float*)d_out;
  hipMemsetAsync(out, 0, (size_t)out_size * sizeof(float), stream);
  istft_fused<<<dim3(TDIM / TT * 8), 256, 0, stream>>>(in, invw, out);
}

// Round 4
// 227.830 us; speedup vs baseline: 1.1894x; 1.0806x over previous
//
#include <hip/hip_runtime.h>
#include <cstddef>

// StreamingISTFT fully fused: staged denorm -> FFT32(k2) -> LDS -> FFT32(k1)
// -> window -> LDS frame tile -> overlap-add -> coalesced stores.
// B=8, F=1024(+Nyquist), T=2048, HOP=512, L=2048.
// irfft(2048) = complex IFFT(1024) (real-packing); IFFT(1024) = 32x32 four-step.
//
// R7:  single-kernel fusion (OLA in-block; boundary columns via atomicAdd).
// R8:  XCD-aware remap: FETCH 446->67 MB, kernel 165->97 us.
// R9:  LDS 67.6->33.8 KB, but launch_bounds(256,4) caused a 22-reg spill.
// R10: frame-split OLA (6-reg carry), no spill -- but kernel flat at ~100 us:
//      VALUBusy 38%, occupancy up, perf unchanged -> waves all stall on the
//      128 scalar global loads/thread in stage 1 (~9 serialized latency
//      exposures; mirror rows loaded twice).
// R11: LDS-staged input. Two 32KB superchunks chosen so Hermitian-mirror rows
//      are IN-chunk (A: rows [0,256)+[768,1024)+row256; B: [256,768)+row768).
//      16 float4 loads/thread (was 128 scalar); denorm ONCE per row during
//      staging (pow_gain 64->32/thread, hidden under load latency); chunk B's
//      loads issued before chunk A's compute -> ~1 latency exposure total.

#define TDIM 2048
#define FDIM 1024
#define TT 8                    // t-columns per block
#define NTOT (512 * 2048)       // output samples per batch
#define SPLANE 4224             // LDS staging plane stride (floats)

static constexpr int kBREV[32] = {0,16,8,24,4,20,12,28,2,18,10,26,6,22,14,30,
                                  1,17,9,25,5,21,13,29,3,19,11,27,7,23,15,31};
// e^{+2*pi*i*r/32}, r=0..15 (inverse-transform sign)
static constexpr float kTR[16] = {
  1.0f, 0.98078528040323044f, 0.92387953251128674f, 0.83146961230254524f,
  0.70710678118654757f, 0.55557023301960218f, 0.38268343236508978f, 0.19509032201612825f,
  0.0f, -0.19509032201612825f, -0.38268343236508978f, -0.55557023301960218f,
  -0.70710678118654757f, -0.83146961230254524f, -0.92387953251128674f, -0.98078528040323044f};
static constexpr float kTI[16] = {
  0.0f, 0.19509032201612825f, 0.38268343236508978f, 0.55557023301960218f,
  0.70710678118654757f, 0.83146961230254524f, 0.92387953251128674f, 0.98078528040323044f,
  1.0f, 0.98078528040323044f, 0.92387953251128674f, 0.83146961230254524f,
  0.70710678118654757f, 0.55557023301960218f, 0.38268343236508978f, 0.19509032201612825f};
// 64th roots of unity: kCC[k2]=cos(2*pi*k2/64), kSS[k2]=sin(2*pi*k2/64)
static constexpr float kCC[32] = {
  1.0f, 0.99518472667219693f, 0.98078528040323044f, 0.95694033573220882f,
  0.92387953251128674f, 0.88192126434835505f, 0.83146961230254524f, 0.77301045336273699f,
  0.70710678118654757f, 0.63439328416364549f, 0.55557023301960218f, 0.47139673682599764f,
  0.38268343236508978f, 0.29028467725446233f, 0.19509032201612825f, 0.098017140329560604f,
  0.0f, -0.098017140329560604f, -0.19509032201612825f, -0.29028467725446233f,
  -0.38268343236508978f, -0.47139673682599764f, -0.55557023301960218f, -0.63439328416364549f,
  -0.70710678118654757f, -0.77301045336273699f, -0.83146961230254524f, -0.88192126434835505f,
  -0.92387953251128674f, -0.95694033573220882f, -0.98078528040323044f, -0.99518472667219693f};
static constexpr float kSS[32] = {
  0.0f, 0.098017140329560604f, 0.19509032201612825f, 0.29028467725446233f,
  0.38268343236508978f, 0.47139673682599764f, 0.55557023301960218f, 0.63439328416364549f,
  0.70710678118654757f, 0.77301045336273699f, 0.83146961230254524f, 0.88192126434835505f,
  0.92387953251128674f, 0.95694033573220882f, 0.98078528040323044f, 0.99518472667219693f,
  1.0f, 0.99518472667219693f, 0.98078528040323044f, 0.95694033573220882f,
  0.92387953251128674f, 0.88192126434835505f, 0.83146961230254524f, 0.77301045336273699f,
  0.70710678118654757f, 0.63439328416364549f, 0.55557023301960218f, 0.47139673682599764f,
  0.38268343236508978f, 0.29028467725446233f, 0.19509032201612825f, 0.098017140329560604f};

template <int H>
__device__ __forceinline__ void fft32_stage(float ar[32], float ai[32]) {
  constexpr int TSTEP = 16 / H;
  #pragma unroll
  for (int g = 0; g < 32; g += 2 * H) {
    #pragma unroll
    for (int j = 0; j < H; ++j) {
      const float twr = kTR[j * TSTEP];
      const float twi = kTI[j * TSTEP];
      const int i0 = g + j, i1 = i0 + H;
      const float tr = twr * ar[i1] - twi * ai[i1];
      const float ti = twr * ai[i1] + twi * ar[i1];
      ar[i1] = ar[i0] - tr; ai[i1] = ai[i0] - ti;
      ar[i0] += tr;         ai[i0] += ti;
    }
  }
}

// In-register radix-2 DIT FFT32 (inverse sign). Input bit-reversed; out natural.
__device__ __forceinline__ void ifft32_core(float ar[32], float ai[32]) {
  fft32_stage<1>(ar, ai);
  fft32_stage<2>(ar, ai);
  fft32_stage<4>(ar, ai);
  fft32_stage<8>(ar, ai);
  fft32_stage<16>(ar, ai);
}

// |v|^(2*PE) * KS via native v_log_f32 + v_exp_f32. v=0 -> 0: ok.
__device__ __forceinline__ float pow_gain(float v, float PE, float KS) {
  return KS * __builtin_amdgcn_exp2f(PE * __builtin_amdgcn_logf(v));
}

__device__ __forceinline__ void denorm4(float4& r, float4& i, float PE, float KS) {
  float g;
  g = pow_gain(r.x * r.x + i.x * i.x, PE, KS); r.x *= g; i.x *= g;
  g = pow_gain(r.y * r.y + i.y * i.y, PE, KS); r.y *= g; i.y *= g;
  g = pow_gain(r.z * r.z + i.z * i.z, PE, KS); r.z *= g; i.z *= g;
  g = pow_gain(r.w * r.w + i.w * i.w, PE, KS); r.w *= g; i.w *= g;
}

// superchunk slot -> global row. SC0: slots [0,256)=rows [0,256), slots
// [256,512)=rows [768,1024), slot 512=row 256. SC1: slot s=row s+256,
// slot 512=row 768.
template <int SC>
__device__ __forceinline__ int slot_row(int s) {
  return (SC == 0) ? (s < 256 ? s : s + 512) : (s + 256);
}

// Stage-1 pack+bitrev for one superchunk's 16 k2 values, reading denormed S
// from LDS. Mirror-slot identities verified: slotm(q>0) = (32-q)+32*(15-u);
// slotm(q==0) = 32*(16-u) with SC0 exceptions u=0 -> 0, u=8 -> 512.
template <int SC>
__device__ __forceinline__ void stage1_compute(const float* __restrict__ Sre,
                                               const float* __restrict__ Sim,
                                               int q, int tl, float wc, float ws,
                                               float ar[32], float ai[32]) {
  #pragma unroll
  for (int u = 0; u < 16; ++u) {
    const int k2 = (SC == 0) ? (u < 8 ? u : u + 16) : (u + 8);
    const int slot = q + 32 * u;
    int slotm_zero = 32 * (16 - u);
    if (SC == 0 && u == 0) slotm_zero = 0;
    if (SC == 0 && u == 8) slotm_zero = 512;
    const int slotm_pos = (32 - q) + 32 * (15 - u);
    const int slotm = (q == 0) ? slotm_zero : slotm_pos;

    const float s1r = Sre[slot * 8 + tl],  s1i = Sim[slot * 8 + tl];
    const float s2r = Sre[slotm * 8 + tl], s2i = Sim[slotm * 8 + tl];
    // W[k] = (S1 + conj(S2)) + i*T*(S1 - conj(S2)),  T = e^{i pi k/1024}
    // T = e^{i pi q/1024} * e^{i pi k2/32}  (constant tables, 4 FMA)
    const float cs = wc * kCC[k2] - ws * kSS[k2];
    const float sn = ws * kCC[k2] + wc * kSS[k2];
    const float Pre = s1r + s2r, Pim = s1i - s2i;
    const float Qre = s1r - s2r, Qim = s1i + s2i;
    const float uu = cs * Qim + sn * Qre;
    const float vv = cs * Qre - sn * Qim;
    float wr = Pre - uu, wi = Pim + vv;
    if (q == 0 && k2 == 0) { wr = s1r; wi = s1r; }  // DC: Im dropped, Nyquist=0
    ar[kBREV[k2]] = wr; ai[kBREV[k2]] = wi;
  }
}

// Half-X layout: X(t, k1, rh) = k1*132 + rh*8 + t (rh in [0,16); 132 = 16*8+4).
#define XH(t, k1, rh) ((k1) * 132 + (rh) * 8 + (t))
#define FSTR 2053               // frame tile row stride (odd -> spread banks)

__global__ __launch_bounds__(256) void istft_fused(const float* __restrict__ in,
                                                   const float* __restrict__ invw,
                                                   float* __restrict__ out) {
  __shared__ float buf[8448];           // 33.8 KB, three overlapped uses:
  float* Sre = buf;                     //  staging: [0,4104) + [4224,8328)
  float* Sim = buf + SPLANE;
  float* Xhr = buf;                     //  X half:  [0,4224) + [4224,8448)
  float* Xhi = buf + 4224;
  float* Fh  = buf;                     //  frames:  [0,8212)

  const int tid = threadIdx.x;
  const int tl  = tid & 7;              // t within tile
  const int q   = tid >> 3;             // k1 (stage 1) / r (stage 2)

  // XCD-aware remap (R8): each XCD owns 32 contiguous t-tiles of one batch.
  const int id   = blockIdx.x;          // 0..2047
  const int xcd  = id & 7;
  const int slot = id >> 3;             // 0..255
  const int b    = slot >> 5;           // 0..7
  const int tile = xcd * 32 + (slot & 31);  // 0..255
  const int t0   = tile * TT;

  const float* re_p = in + ((size_t)b * 2 + 0) * ((size_t)FDIM * TDIM);
  const float* im_p = in + ((size_t)b * 2 + 1) * ((size_t)FDIM * TDIM);

  const float KS = (float)(exp((-1.0 / 0.65) * log(0.06)) / 2048.0);
  const float PE = 7.0f / 26.0f;

  // pack twiddle base: e^{i*pi*q/1024}
  const float aq = 3.0679615757712824e-3f * (float)q;
  const float wc = __cosf(aq), ws = __sinf(aq);

  float ar[32], ai[32];

  // ---- Stage 1a: load + denorm superchunk A; stage to LDS ----
  float4 reA[4], imA[4];
  #pragma unroll
  for (int j = 0; j < 4; ++j) {
    const int f = tid + 256 * j;
    const int s = f >> 1, cg = f & 1;
    const int row = slot_row<0>(s);
    reA[j] = *(const float4*)(re_p + (size_t)row * TDIM + t0 + 4 * cg);
    imA[j] = *(const float4*)(im_p + (size_t)row * TDIM + t0 + 4 * cg);
  }
  float4 exRe, exIm;                    // extra row 256 -> slot 512 (tid<2)
  if (tid < 2) {
    exRe = *(const float4*)(re_p + (size_t)256 * TDIM + t0 + 4 * tid);
    exIm = *(const float4*)(im_p + (size_t)256 * TDIM + t0 + 4 * tid);
  }
  #pragma unroll
  for (int j = 0; j < 4; ++j) {
    const int f = tid + 256 * j;
    const int s = f >> 1, cg = f & 1;
    denorm4(reA[j], imA[j], PE, KS);
    *(float4*)(Sre + s * 8 + 4 * cg) = reA[j];
    *(float4*)(Sim + s * 8 + 4 * cg) = imA[j];
  }
  if (tid < 2) {
    denorm4(exRe, exIm, PE, KS);
    *(float4*)(Sre + 512 * 8 + 4 * tid) = exRe;
    *(float4*)(Sim + 512 * 8 + 4 * tid) = exIm;
  }

  // ---- issue superchunk B global loads now (consumed after compute A) ----
  float4 reB[4], imB[4];
  #pragma unroll
  for (int j = 0; j < 4; ++j) {
    const int f = tid + 256 * j;
    const int s = f >> 1, cg = f & 1;
    const int row = slot_row<1>(s);
    reB[j] = *(const float4*)(re_p + (size_t)row * TDIM + t0 + 4 * cg);
    imB[j] = *(const float4*)(im_p + (size_t)row * TDIM + t0 + 4 * cg);
  }
  float4 exReB, exImB;                  // extra row 768 -> slot 512 (tid<2)
  if (tid < 2) {
    exReB = *(const float4*)(re_p + (size_t)768 * TDIM + t0 + 4 * tid);
    exImB = *(const float4*)(im_p + (size_t)768 * TDIM + t0 + 4 * tid);
  }
  __syncthreads();

  // ---- Stage 1b: compute superchunk A (k2 in [0,8) u [24,32)) ----
  stage1_compute<0>(Sre, Sim, q, tl, wc, ws, ar, ai);
  __syncthreads();                      // all A reads done before B overwrites

  // ---- Stage 1c: stage superchunk B; compute (k2 in [8,24)) ----
  #pragma unroll
  for (int j = 0; j < 4; ++j) {
    const int f = tid + 256 * j;
    const int s = f >> 1, cg = f & 1;
    denorm4(reB[j], imB[j], PE, KS);
    *(float4*)(Sre + s * 8 + 4 * cg) = reB[j];
    *(float4*)(Sim + s * 8 + 4 * cg) = imB[j];
  }
  if (tid < 2) {
    denorm4(exReB, exImB, PE, KS);
    *(float4*)(Sre + 512 * 8 + 4 * tid) = exReB;
    *(float4*)(Sim + 512 * 8 + 4 * tid) = exImB;
  }
  __syncthreads();
  stage1_compute<1>(Sre, Sim, q, tl, wc, ws, ar, ai);
  __syncthreads();                      // staging dead; X may overwrite buf

  // ---- FFT32 over k2 ----
  ifft32_core(ar, ai);

  // ---- Transpose through half-size X (r-split) ----
  float zr[32], zi[32];
  #pragma unroll
  for (int r = 0; r < 16; ++r) {        // half A, twiddle e^{2 pi i q r/1024}
    const float ang = 6.1359231515425649e-3f * (float)(q * r);
    const float sn = __sinf(ang), cs = __cosf(ang);
    Xhr[XH(tl, q, r)] = cs * ar[r] - sn * ai[r];
    Xhi[XH(tl, q, r)] = cs * ai[r] + sn * ar[r];
  }
  __syncthreads();
  if (q < 16) {                         // waves 0-1 read their stage-2 input
    #pragma unroll
    for (int i = 0; i < 32; ++i) {
      zr[i] = Xhr[XH(tl, kBREV[i], q)];
      zi[i] = Xhi[XH(tl, kBREV[i], q)];
    }
  }
  __syncthreads();
  #pragma unroll
  for (int r = 16; r < 32; ++r) {       // half B
    const float ang = 6.1359231515425649e-3f * (float)(q * r);
    const float sn = __sinf(ang), cs = __cosf(ang);
    Xhr[XH(tl, q, r - 16)] = cs * ar[r] - sn * ai[r];
    Xhi[XH(tl, q, r - 16)] = cs * ai[r] + sn * ar[r];
  }
  __syncthreads();
  if (q >= 16) {                        // waves 2-3 read their stage-2 input
    #pragma unroll
    for (int i = 0; i < 32; ++i) {
      zr[i] = Xhr[XH(tl, kBREV[i], q - 16)];
      zi[i] = Xhi[XH(tl, kBREV[i], q - 16)];
    }
  }
  __syncthreads();                      // X dead; F tile may overwrite buf

  // ---- Stage 2: FFT32 over k1 ----
  ifft32_core(zr, zi);

  // ---- Frame-split OLA: frames tt in [0,4) then [4,8) (R10) ----
  float* ob = out + (size_t)b * NTOT;
  float acc[3][2];

  if (tl < 4) {                         // F phase A: frames 0..3
    #pragma unroll
    for (int s = 0; s < 32; ++s) {
      const int l0 = 2 * q + 64 * s;
      Fh[tl * FSTR + l0]     = zr[s] * invw[l0];
      Fh[tl * FSTR + l0 + 1] = zi[s] * invw[l0 + 1];
    }
  }
  __syncthreads();
  #pragma unroll
  for (int rel = 0; rel < 7; ++rel) {   // OLA A: contributors tt in [0,4)
    #pragma unroll
    for (int half = 0; half < 2; ++half) {
      const int j = tid + 256 * half;
      float v = 0.0f;
      #pragma unroll
      for (int c = 0; c < 4; ++c) {
        const int tt = rel - c;
        if (tt >= 0 && tt < 4) v += Fh[tt * FSTR + j + 512 * c];
      }
      if (rel < 3)       atomicAdd(&ob[(t0 + rel) * 512 + j], v);  // boundary
      else if (rel == 3) ob[(t0 + rel) * 512 + j] = v;             // complete
      else               acc[rel - 4][half] = v;                   // carry 4..6
    }
  }
  __syncthreads();
  if (tl >= 4) {                        // F phase B: frames 4..7 at row tl-4
    #pragma unroll
    for (int s = 0; s < 32; ++s) {
      const int l0 = 2 * q + 64 * s;
      Fh[(tl - 4) * FSTR + l0]     = zr[s] * invw[l0];
      Fh[(tl - 4) * FSTR + l0 + 1] = zi[s] * invw[l0 + 1];
    }
  }
  __syncthreads();
  #pragma unroll
  for (int rel = 4; rel < 11; ++rel) {  // OLA B: contributors tt in [4,8)
    const int tp = t0 + rel;
    if (tp > 2047) continue;
    #pragma unroll
    for (int half = 0; half < 2; ++half) {
      const int j = tid + 256 * half;
      float v = (rel < 7) ? acc[rel - 4][half] : 0.0f;
      #pragma unroll
      for (int c = 0; c < 4; ++c) {
        const int tt = rel - c;
        if (tt >= 4 && tt < 8) v += Fh[(tt - 4) * FSTR + j + 512 * c];
      }
      const int n = tp * 512 + j;
      if (rel <= 7) ob[n] = v;          // all 4 contributors seen in-block
      else atomicAdd(&ob[n], v);        // tile boundary: 2 writers
    }
  }
}

extern "C" void kernel_launch(void* const* d_in, const int* in_sizes, int n_in,
                              void* d_out, int out_size, void* d_ws, size_t ws_size,
                              hipStream_t stream) {
  (void)in_sizes; (void)n_in; (void)d_ws; (void)ws_size;
  const float* in   = (const float*)d_in[0];
  const float* invw = (const float*)d_in[1];
  float* out = (float*)d_out;
  hipMemsetAsync(out, 0, (size_t)out_size * sizeof(float), stream);
  istft_fused<<<dim3(TDIM / TT * 8), 256, 0, stream>>>(in, invw, out);
}